// Round 6
// baseline (223.279 us; speedup 1.0000x reference)
//
#include <hip/hip_runtime.h>

#define T_MAX 512
#define BATCH 32
#define CLASSES 1296
#define L_MAX 64
#define NROWS (T_MAX * BATCH)   // 16384
#define NV4 (CLASSES / 4)       // 324
#define NINF (-INFINITY)

// DPP wave64 sum: row_shr 1/2/4/8 + row_bcast 15/31. Total lands in LANE 63.
__device__ __forceinline__ float wave_sum64(float v) {
    v += __int_as_float(__builtin_amdgcn_update_dpp(0, __float_as_int(v), 0x111, 0xF, 0xF, true));
    v += __int_as_float(__builtin_amdgcn_update_dpp(0, __float_as_int(v), 0x112, 0xF, 0xF, true));
    v += __int_as_float(__builtin_amdgcn_update_dpp(0, __float_as_int(v), 0x114, 0xF, 0xF, true));
    v += __int_as_float(__builtin_amdgcn_update_dpp(0, __float_as_int(v), 0x118, 0xF, 0xF, true));
    v += __int_as_float(__builtin_amdgcn_update_dpp(0, __float_as_int(v), 0x142, 0xF, 0xF, true));
    v += __int_as_float(__builtin_amdgcn_update_dpp(0, __float_as_int(v), 0x143, 0xF, 0xF, true));
    return v;
}

// async global->LDS, 16 B per lane. Dest is wave-uniform base + lane*16.
__device__ __forceinline__ void glds16(const float* g, float* l) {
    __builtin_amdgcn_global_load_lds((const __attribute__((address_space(1))) void*)g,
                                     (__attribute__((address_space(3))) void*)l, 16, 0, 0);
}

// ---------------------------------------------------------------------------
// K1 v5: wave per (pred row, seq row) pair. Rows staged via global_load_lds
// (VGPR-free async DMA -> all 10 KB/wave guaranteed in flight; the compiler
// cannot re-serialize this). 3 blocks/CU x 10.4 KB/wave = ~125 KB outstanding
// per CU. Readback from LDS (b128, conflict-free), DPP reduce, LDS gather.
// ---------------------------------------------------------------------------
__global__ __launch_bounds__(256, 1) void rowstats_kernel(
    const float* __restrict__ pred, const float* __restrict__ seqp,
    const int* __restrict__ label,
    float* __restrict__ lse_pred, float* __restrict__ sum_pred,
    float* __restrict__ lse_seq, float* __restrict__ pb, int* __restrict__ counter)
{
    __shared__ float st[4][2592];                  // [wave][pred 0..1295 | seq 1296..2591]
    int w = threadIdx.x >> 6, lane = threadIdx.x & 63;
    int r = blockIdx.x * 4 + w;                    // row in [0, NROWS)
    if (r == 0 && lane == 0) *counter = 0;         // for ce's last-block reduce
    const float* xp = pred + (size_t)r * CLASSES;
    const float* xs = seqp + (size_t)r * CLASSES;
    float* lp_ = st[w];
    float* ls_ = st[w] + 1296;

    // ---- issue phase: 10 async 1-KB chunks + 2 tail float4 + label, all in flight
    #pragma unroll
    for (int k = 0; k < 5; ++k) glds16(xp + k * 256 + lane * 4, lp_ + k * 256);
    #pragma unroll
    for (int k = 0; k < 5; ++k) glds16(xs + k * 256 + lane * 4, ls_ + k * 256);
    float4 tp = make_float4(0.f, 0.f, 0.f, 0.f);
    float4 ts = make_float4(0.f, 0.f, 0.f, 0.f);
    if (lane < 4) {
        tp = ((const float4*)xp)[320 + lane];      // floats 1280..1295
        ts = ((const float4*)xs)[320 + lane];
    }
    int lab = label[((r & 31) << 6) + lane];
    __asm__ __volatile__("s_waitcnt vmcnt(0)" ::: "memory");

    // ---- compute from LDS ----
    const float4* lp4 = (const float4*)lp_;
    const float4* ls4 = (const float4*)ls_;
    float sp = 0.f, sx = 0.f, ss = 0.f;
    #pragma unroll
    for (int k = 0; k < 5; ++k) {
        float4 a = lp4[lane + (k << 6)];
        float4 b2 = ls4[lane + (k << 6)];
        sp += __expf(a.x) + __expf(a.y) + __expf(a.z) + __expf(a.w);
        sx += a.x + a.y + a.z + a.w;
        ss += __expf(b2.x) + __expf(b2.y) + __expf(b2.z) + __expf(b2.w);
    }
    if (lane < 4) {
        sp += __expf(tp.x) + __expf(tp.y) + __expf(tp.z) + __expf(tp.w);
        sx += tp.x + tp.y + tp.z + tp.w;
        ss += __expf(ts.x) + __expf(ts.y) + __expf(ts.z) + __expf(ts.w);
    }
    sp = wave_sum64(sp);
    sx = wave_sum64(sx);
    ss = wave_sum64(ss);

    int b = r & 31, t = r >> 5;
    float sv = (lab < 1280) ? ls_[lab]
             : ((lab - 1280) == ((lane < 4) ? -1 : -1), ls_[lab]);  // LDS holds full row? no
    // NOTE: LDS only holds floats 0..1279 of seq; tail 1280..1295 lives in ts of lanes 0..3.
    // Handle: if lab >= 1280, read directly from global (L2-warm, rare: 16/1296 ~ 1.2%).
    if (lab >= 1280) sv = xs[lab];
    pb[(((size_t)(b << 9) + t) << 6) + lane] = sv;
    if (lane == 63) {
        lse_pred[r] = __logf(sp);
        sum_pred[r] = sx;
        lse_seq[r]  = __logf(ss);
    }
}

// ---------------------------------------------------------------------------
// K2 v3 (unchanged from R5 -- validated absmax 0.0): minimal-chain DP.
// ---------------------------------------------------------------------------
__global__ __launch_bounds__(128) void align_kernel(
    const float* __restrict__ pb, const int* __restrict__ x_len,
    const int* __restrict__ label_len, int* __restrict__ tg)
{
    int b = blockIdx.x;
    int tid = threadIdx.x, w = tid >> 6, lane = tid & 63;
    int C = x_len[b], R = label_len[b];
    int limit = C - R;
    __shared__ float buf[2][4096];       // two 64-col panels (32 KB)
    __shared__ uint2 chw[8 * 64];        // per-panel per-lane choice bits (4 KB)
    __shared__ int a_s[64];              // interval start per row
    __shared__ int rows_s[T_MAX];
    const float* pbb = pb + ((size_t)b << 15);   // b * 512 * 64
    int P = (C + 63) >> 6;

    int l0 = (lane & 15) << 2;
    bool mk0 = (l0 + 0) < R, mk1 = (l0 + 1) < R, mk2 = (l0 + 2) < R, mk3 = (l0 + 3) < R;
    bool isb0 = (lane & 15) == 0;
    const int ninf_i = 0xFF800000;

    if (w == 1) {                        // prologue: stage panel 0 (masked)
        const float4* s4 = (const float4*)pbb;
        float4* d4 = (float4*)buf[0];
        #pragma unroll
        for (int k = 0; k < 16; ++k) {
            float4 q = s4[(k << 6) + lane];
            q.x = mk0 ? q.x : NINF;  q.y = mk1 ? q.y : NINF;
            q.z = mk2 ? q.z : NINF;  q.w = mk3 ? q.w : NINF;
            d4[(k << 6) + lane] = q;
        }
    }
    __syncthreads();

    float dp = NINF;
    for (int p = 0; p < P; ++p) {
        if (w == 1) {
            int ldp = p + 1; if (ldp > 7) ldp = 7;
            const float4* s4 = (const float4*)(pbb + (ldp << 12));
            float4* d4 = (float4*)buf[(p + 1) & 1];
            #pragma unroll
            for (int k = 0; k < 16; ++k) {
                float4 q = s4[(k << 6) + lane];
                q.x = mk0 ? q.x : NINF;  q.y = mk1 ? q.y : NINF;
                q.z = mk2 ? q.z : NINF;  q.w = mk3 ? q.w : NINF;
                d4[(k << 6) + lane] = q;
            }
        } else {
            const float* bc = buf[p & 1];
            int base = p << 6;
            unsigned w0 = 0, w1 = 0;
            #pragma unroll
            for (int g = 0; g < 4; ++g) {
                float v[16];
                #pragma unroll
                for (int u = 0; u < 16; ++u) v[u] = bc[((g << 4) + u) * 64 + lane];
                bool general = (p == 0) || (base + (g << 4) + 15 > limit);
                #pragma unroll
                for (int u = 0; u < 16; ++u) {
                    int kk = (g << 4) + u;
                    int j = base + kk;
                    float val;
                    if (general) {
                        if (p == 0 && kk == 0) {
                            dp = (lane == 0) ? v[0] : NINF;
                            continue;
                        }
                        bool ib = (lane <= j) && (lane >= j - limit);
                        val = ib ? v[u] : NINF;
                    } else {
                        val = v[u];
                    }
                    int dpb = __float_as_int(dp);
                    int t1 = __builtin_amdgcn_update_dpp(ninf_i, dpb, 0x111, 0xF, 0xF, false);
                    int t2 = __builtin_amdgcn_update_dpp(ninf_i, dpb, 0x142, 0xF, 0xF, false);
                    float shifted = __int_as_float(isb0 ? t2 : t1);
                    bool c = shifted > dp;
                    unsigned bit01 = c ? 1u : 0u;
                    if (kk < 32) w0 |= bit01 << kk; else w1 |= bit01 << (kk - 32);
                    dp = fmaxf(shifted, dp) + val;
                }
            }
            chw[(p << 6) + lane] = make_uint2(w0, w1);
        }
        __syncthreads();
    }

    if (tid == 0) {
        const unsigned* ch32 = (const unsigned*)chw;
        int row = R - 1, j = C - 1;
        while (row > 0 && j >= 0) {
            unsigned word = ch32[((j >> 6) << 7) + (row << 1) + ((j >> 5) & 1)];
            unsigned mb = (2u << (j & 31)) - 1;
            unsigned m = word & mb;
            if (m) {
                int hb = 31 - __clz(m);
                int aj = (j & ~31) | hb;
                a_s[row] = aj;
                row--; j = aj - 1;
            } else {
                j = (j & ~31) - 1;
            }
        }
        for (int i = row; i >= 0; --i) a_s[i] = 0;
    }
    __syncthreads();
    if (tid < R) {
        int a = a_s[tid];
        int bi = (tid == R - 1) ? (C - 1) : (a_s[tid + 1] - 1);
        for (int j = a; j <= bi; ++j) rows_s[j] = tid;
    }
    __syncthreads();
    for (int j = tid; j < T_MAX; j += 128)
        tg[(b << 9) + j] = (j < C) ? rows_s[j] : -1;
}

// ---------------------------------------------------------------------------
// K3: per-element CE + fused last-block final reduction (agent-scope atomics).
// ---------------------------------------------------------------------------
__global__ __launch_bounds__(256) void ce_kernel(
    const float* __restrict__ pred, const int* __restrict__ label,
    const int* __restrict__ x_len,
    const float* __restrict__ lse_pred, const float* __restrict__ sum_pred,
    const float* __restrict__ lse_seq, const float* __restrict__ pb,
    const int* __restrict__ tg, float* __restrict__ partials,
    int* __restrict__ counter, float* __restrict__ out)
{
    int e = blockIdx.x * 256 + threadIdx.x;    // e = t*BATCH + b
    int t = e >> 5, b = e & 31;
    float ce = 0.f;
    if (t < x_len[b]) {
        int row = tg[(b << 9) + t];
        int tgt = label[(b << 6) + row];
        float lp = lse_pred[e];
        float S = sum_pred[e] - (float)CLASSES * lp;
        float lsp_t = pred[(size_t)e * CLASSES + tgt] - lp;
        float conf = __expf(pb[(((size_t)(b << 9) + t) << 6) + row] - lse_seq[e]);
        float smooth = (1.f - conf) * (1.f / (float)(CLASSES - 1));
        ce = -((conf - smooth) * lsp_t + smooth * S);
    }
    ce = wave_sum64(ce);
    __shared__ float sm[4];
    __shared__ int amLast;
    if ((threadIdx.x & 63) == 63) sm[threadIdx.x >> 6] = ce;
    __syncthreads();
    if (threadIdx.x == 0) {
        float p = sm[0] + sm[1] + sm[2] + sm[3];
        __hip_atomic_store(&partials[blockIdx.x], p, __ATOMIC_RELEASE, __HIP_MEMORY_SCOPE_AGENT);
        amLast = (__hip_atomic_fetch_add(counter, 1, __ATOMIC_ACQ_REL, __HIP_MEMORY_SCOPE_AGENT) == 63);
    }
    __syncthreads();
    if (amLast && threadIdx.x < 64) {
        float v = __hip_atomic_load(&partials[threadIdx.x], __ATOMIC_ACQUIRE, __HIP_MEMORY_SCOPE_AGENT);
        for (int o = 32; o; o >>= 1) v += __shfl_down(v, o, 64);
        if (threadIdx.x == 0) out[0] = v * (1.0f / (float)NROWS);
    }
}

extern "C" void kernel_launch(void* const* d_in, const int* in_sizes, int n_in,
                              void* d_out, int out_size, void* d_ws, size_t ws_size,
                              hipStream_t stream) {
    const float* pred      = (const float*)d_in[0];
    const float* seq_pred  = (const float*)d_in[1];
    const int*   label     = (const int*)d_in[2];
    const int*   x_len     = (const int*)d_in[3];
    const int*   label_len = (const int*)d_in[4];
    float* out = (float*)d_out;

    // workspace layout (floats)
    float* w = (float*)d_ws;
    float* lse_pred = w;                       // 16384
    float* sum_pred = w + NROWS;               // 16384
    float* lse_seq  = w + 2 * NROWS;           // 16384
    float* pb       = w + 3 * NROWS;           // 32*512*64 = 1048576
    int*   tg       = (int*)(w + 3 * NROWS + (size_t)BATCH * T_MAX * 64); // 16384 ints
    float* partials = (float*)(tg + NROWS);    // 64
    int*   counter  = (int*)(partials + 64);   // 1

    rowstats_kernel<<<NROWS / 4, 256, 0, stream>>>(pred, seq_pred, label,
                                                   lse_pred, sum_pred, lse_seq, pb, counter);
    align_kernel<<<BATCH, 128, 0, stream>>>(pb, x_len, label_len, tg);
    ce_kernel<<<64, 256, 0, stream>>>(pred, label, x_len,
                                      lse_pred, sum_pred, lse_seq, pb, tg,
                                      partials, counter, out);
}